// Round 7
// baseline (206.507 us; speedup 1.0000x reference)
//
#include <hip/hip_runtime.h>
#include <math.h>

#define DD 64
#define LL 2048
#define HEADS 32
#define TQ 128
#define TK 64
#define NT (LL / TK)             // 32 k-tiles
#define NTHREADS 512
// 1/sqrt(64) * log2(e), folded into Q at staging (leaky commutes with positive scale)
#define QSCALE 0.18033688011112042f

typedef __bf16 bf16_t;
typedef __bf16 bf16x8 __attribute__((ext_vector_type(8)));
typedef float f32x16 __attribute__((ext_vector_type(16)));

// ============================================================================
// Prepass v2 (K,V only):
//   z=0: KT[head][l][d]          = k[head][d][l]  (transposed, bf16; k-tile t
//                                  occupies a contiguous 8KB block = rows t*64..)
//   z=1: VT[head][t][d][lk]      = v[head][d][t*64+lk]  (TILE-BLOCKED: per
//                                  64-key tile a contiguous [64d][64lk] 8KB
//                                  block; lane reads become 128B-row-stride —
//                                  L1-friendly, no 4KB set aliasing)
// ~33.5 MB read + 16.8 MB write => ~8 us memory-bound.
// ============================================================================
__global__ __launch_bounds__(256)
void prep_bf16_kv2(const float* __restrict__ k, const float* __restrict__ v,
                   bf16_t* __restrict__ kt, bf16_t* __restrict__ vt) {
  __shared__ float ld[64][65];
  const int t = threadIdx.x;
  const int which = blockIdx.z;
  const int head = blockIdx.y;
  const int l0 = blockIdx.x * 64;           // one 64-key tile per block
  const size_t hoff = (size_t)head * DD * LL;
  if (which == 1) {
    // V: convert + tile-block. dst tile base = (l0/64)*DD*64.
    const float* src = v + hoff;
    bf16_t* dst = vt + hoff + (size_t)(l0 >> 6) * (DD * 64);
    const int lp = (t & 31) * 2;            // 0..62 within tile
    const int db = (t >> 5) * 8;
    for (int i = 0; i < 8; ++i) {
      int d = db + i;
      float2 x = *(const float2*)(src + (size_t)d * LL + l0 + lp);
      union { bf16_t b[2]; unsigned u; } pk;
      pk.b[0] = (bf16_t)x.x;
      pk.b[1] = (bf16_t)x.y;
      *(unsigned*)(dst + d * 64 + lp) = pk.u;   // coalesced 128B per d-row
    }
  } else {
    // K: 64x64 tile transpose through LDS (pad 65: conflict-free)
    const float* src = k + hoff;
    bf16_t* dst = kt + hoff;
    const int l = t & 63;
    const int db = (t >> 6) * 16;
    for (int i = 0; i < 16; ++i) {
      int d = db + i;
      ld[l][d] = src[(size_t)d * LL + l0 + l];  // coalesced along l
    }
    __syncthreads();
    const int dp = (t & 31) * 2;
    const int lb = (t >> 5) * 8;
    for (int i = 0; i < 8; ++i) {
      int lw = lb + i;
      union { bf16_t b[2]; unsigned u; } pk;
      pk.b[0] = (bf16_t)ld[lw][dp];
      pk.b[1] = (bf16_t)ld[lw][dp + 1];
      *(unsigned*)(dst + (size_t)(l0 + lw) * DD + dp) = pk.u;  // coalesced along d
    }
  }
}

// ============================================================================
// Main kernel v8: NO LDS, NO BARRIERS in the k-loop.
// Rationale: round-6 null result proved per-CU throughput is invariant to
// blocks/CU — the barrier-lockstep staging is the cap, and K/V are fully
// L2-resident per XCD (round-4: FETCH = ideal 16.4 MB). So read MFMA
// fragments DIRECTLY from L1/L2 (guide m169: dropping staging of L2-fit
// data was +26% on attn):
//   ak(t+1) loads issued right after QK(t) consumes ak — latency hides
//   under softmax+PV; bv(t+1) issued after PV(t) — hides under next
//   QK+softmax. Register rotate, no extra buffers. Waves drift freely
//   (setprio now has arbitration room — m191 regime).
// LDS only for Q staging + epilogue (union, 33.3 KB).
// Keeps: XCD pinning, fp32 Q staged in-kernel, rsl[4] split sums, v5 epilogue.
// ============================================================================
union __align__(16) SMemU8 {
  bf16_t Qs[TQ][72];         // [lq][d] pre-scaled bf16 (dead after bq hoist)
  float Oe[TQ][65];          // epilogue combine/transpose buffer (33.3 KB)
};

__global__ __launch_bounds__(NTHREADS, 4)
void attn_flash_nolds(const float* __restrict__ q, const bf16_t* __restrict__ kt,
                      const bf16_t* __restrict__ vt, float* __restrict__ out) {
  __shared__ SMemU8 sm;
  __shared__ float rs1[TQ];
  const int tid  = threadIdx.x;
  const int w    = tid >> 6;        // wave 0..7
  const int lane = tid & 63;
  const int l31  = lane & 31;
  const int hh   = lane >> 5;       // half of wave
  const int strip = w & 3;          // lq strip 0..3
  const int half  = w >> 2;         // lk half 0/1
  const int wbase = strip * 32;
  const int lkh   = half * 32;
  // ---- XCD-aware decode: bid%8 pins head%8 => per-XCD L2-resident K/V ----
  const int bid  = blockIdx.x;
  const int j    = bid >> 3;
  const int head = (bid & 7) + 8 * (j >> 4);
  const int q0   = (j & 15) * TQ;
  const size_t hoff = (size_t)head * DD * LL;
  const float*  qp = q  + hoff;

  // per-lane fragment base pointers (element units); tile t adds t*4096
  //   K^T[lk][d]: lane reads 16B at row (lkh+l31), d-chunk kk*16+8*hh
  const bf16_t* kl = kt + hoff + (size_t)(lkh + l31) * 64 + hh * 8;
  //   V tile [d][lk]: lane reads 16B at d-row (dt*32+l31), lk-chunk lkh+kk2*16+8*hh
  const bf16_t* vl = vt + hoff + (size_t)l31 * 64 + lkh + hh * 8;

  // ---- preload tile 0 fragments (in flight under Q staging) ----
  bf16x8 ak[4], bv[4];
#pragma unroll
  for (int kk = 0; kk < 4; ++kk)
    ak[kk] = *(const bf16x8*)(kl + kk * 16);
#pragma unroll
  for (int i = 0; i < 4; ++i)                 // i = dt*2 + kk2
    bv[i] = *(const bf16x8*)(vl + (i >> 1) * 2048 + (i & 1) * 16);

  // ---- stage Q transposed from fp32: lanes along lq => coalesced 512B lines ----
  {
    int lq  = tid & 127;
    int d0q = (tid >> 7) * 16;
    const float* src = qp + q0 + lq;
    for (int g = 0; g < 2; ++g) {
      bf16x8 pk;
      for (int jj = 0; jj < 8; ++jj)
        pk[jj] = (bf16_t)(src[(size_t)(d0q + g * 8 + jj) * LL] * QSCALE);
      *(bf16x8*)&sm.Qs[lq][d0q + g * 8] = pk;
    }
  }

  __syncthreads();   // Q staged (only barrier before epilogue)
  bf16x8 bq[4];
  for (int kk = 0; kk < 4; ++kk)
    bq[kk] = *(const bf16x8*)&sm.Qs[wbase + l31][kk * 16 + 8 * hh];
  // Qs (union w/ Oe) is dead from here; Oe writes happen after epilogue barrier.

  f32x16 oacc[2];
  for (int dt = 0; dt < 2; ++dt)
    for (int r = 0; r < 16; ++r) oacc[dt][r] = 0.f;
  float rsl[4];
  for (int i = 0; i < 4; ++i) rsl[i] = 0.f;

  for (int t = 0; t < NT; ++t) {
    const int tn = (t + 1 < NT) ? t + 1 : t;   // clamped prefetch tile (branchless)

    // ---- S^T = K^T Q over this wave's lk half (ak resident) ----
    f32x16 st;
    for (int r = 0; r < 16; ++r) st[r] = 0.f;
    __builtin_amdgcn_s_setprio(1);
    for (int kk = 0; kk < 4; ++kk)
      st = __builtin_amdgcn_mfma_f32_32x32x16_bf16(ak[kk], bq[kk], st, 0, 0, 0);
    __builtin_amdgcn_s_setprio(0);

    // ---- issue ak(t+1): latency hides under softmax + PV ----
#pragma unroll
    for (int kk = 0; kk < 4; ++kk)
      ak[kk] = *(const bf16x8*)(kl + (size_t)tn * 4096 + kk * 16);

    // ---- leaky + exp2 in registers (4-way split sum) ----
    unsigned pb[8];
#pragma unroll
    for (int r = 0; r < 16; ++r) {
      float s = st[r];
      s = fmaxf(s, 0.01f * s);
      float p = __builtin_amdgcn_exp2f(s);
      rsl[r & 3] += p;
      st[r] = p;
    }
    for (int qq = 0; qq < 8; ++qq) {
      union { bf16_t b[2]; unsigned u; } pk;
      pk.b[0] = (bf16_t)st[2 * qq];
      pk.b[1] = (bf16_t)st[2 * qq + 1];
      pb[qq] = pk.u;
    }

    // ---- PV over this wave's lk half (bv resident): one cross-half exchange ----
    for (int kk2 = 0; kk2 < 2; ++kk2) {
      unsigned l0 = pb[4 * kk2 + 0], l1 = pb[4 * kk2 + 1];
      unsigned l2 = pb[4 * kk2 + 2], l3 = pb[4 * kk2 + 3];
      unsigned s0 = hh ? l0 : l2;
      unsigned s1 = hh ? l1 : l3;
      unsigned f0 = (unsigned)__shfl_xor((int)s0, 32);
      unsigned f1 = (unsigned)__shfl_xor((int)s1, 32);
      union { unsigned u[4]; bf16x8 v; } ap;
      ap.u[0] = hh ? f0 : l0;
      ap.u[1] = hh ? f1 : l1;
      ap.u[2] = hh ? l2 : f0;
      ap.u[3] = hh ? l3 : f1;
      __builtin_amdgcn_s_setprio(1);
      for (int dt = 0; dt < 2; ++dt)
        oacc[dt] = __builtin_amdgcn_mfma_f32_32x32x16_bf16(ap.v, bv[dt * 2 + kk2],
                                                           oacc[dt], 0, 0, 0);
      __builtin_amdgcn_s_setprio(0);
    }

    // ---- issue bv(t+1): latency hides under next QK + softmax ----
#pragma unroll
    for (int i = 0; i < 4; ++i)
      bv[i] = *(const bf16x8*)(vl + (size_t)tn * 4096 + (i >> 1) * 2048 + (i & 1) * 16);
  }

  // ---- epilogue: combine lk-half pairs, normalize, transpose, store (v5) ----
  float rsum = (rsl[0] + rsl[1]) + (rsl[2] + rsl[3]);
  float rtot = rsum + __shfl_xor(rsum, 32);   // both hh row-groups of this wave
  __syncthreads();                            // all bq hoists done; union safe
  if (half == 1) {
    rs1[wbase + l31] = rtot;
    for (int r = 0; r < 16; ++r) {
      int row = (r & 3) + 8 * (r >> 2) + 4 * hh;
      for (int dt = 0; dt < 2; ++dt)
        sm.Oe[wbase + row][dt * 32 + l31] = oacc[dt][r];
    }
  }
  __syncthreads();
  if (half == 0) {
    float tot = rtot + rs1[wbase + l31];
    rs1[wbase + l31] = 1.0f / tot;            // same-lane read-then-write: safe in-wave
    float inv[16];
    for (int r = 0; r < 16; ++r) {
      int row = (r & 3) + 8 * (r >> 2) + 4 * hh;
      inv[r] = rs1[wbase + row];              // in-wave broadcast reads
    }
    for (int r = 0; r < 16; ++r) {
      int row = (r & 3) + 8 * (r >> 2) + 4 * hh;
      for (int dt = 0; dt < 2; ++dt) {
        int col = dt * 32 + l31;
        sm.Oe[wbase + row][col] = (oacc[dt][r] + sm.Oe[wbase + row][col]) * inv[r];
      }
    }
  }
  __syncthreads();
  float* op = out + hoff + q0;
  for (int i = 0; i < 16; ++i) {
    int idx = tid + NTHREADS * i;  // 0..8191
    int d   = idx >> 7;
    int lq  = idx & 127;
    op[(size_t)d * LL + lq] = sm.Oe[lq][d];   // coalesced: lanes -> consecutive lq
  }
}

// ============================================================================
// Fallback: the original harness-verified fp32-input kernel (no workspace).
// ============================================================================
struct __align__(16) SMemA {
  bf16_t Qs[TQ][72];
  bf16_t Ks[TK][72];
  bf16_t Vs[DD][72];
};
union __align__(16) SMemU {
  SMemA a;
  float Oe[TQ][65];
};

__global__ __launch_bounds__(NTHREADS, 4)
void attn_flash_bf16(const float* __restrict__ q, const float* __restrict__ k,
                     const float* __restrict__ v, float* __restrict__ out) {
  __shared__ SMemU sm;
  __shared__ float rs1[TQ];
  const int tid  = threadIdx.x;
  const int w    = tid >> 6;
  const int lane = tid & 63;
  const int l31  = lane & 31;
  const int hh   = lane >> 5;
  const int strip = w & 3;
  const int half  = w >> 2;
  const int wbase = strip * 32;
  const int lkh   = half * 32;
  const int head = blockIdx.y;
  const int q0   = blockIdx.x * TQ;
  const size_t hoff = (size_t)head * DD * LL;
  const float* qp = q + hoff;
  const float* kp = k + hoff;
  const float* vp = v + hoff;

  {
    int lq  = tid & 127;
    int d0q = (tid >> 7) * 16;
    const float* src = qp + q0 + lq;
    for (int g = 0; g < 2; ++g) {
      bf16x8 pk;
      for (int jj = 0; jj < 8; ++jj)
        pk[jj] = (bf16_t)(src[(size_t)(d0q + g * 8 + jj) * LL] * QSCALE);
      *(bf16x8*)&sm.a.Qs[lq][d0q + g * 8] = pk;
    }
  }

  const int klk = tid & 63;
  const int kd0 = (tid >> 6) * 8;
  const int vd  = tid >> 3;
  const int vc8 = (tid & 7) * 8;

  float  kreg[8];
  float4 vreg[2];
  {
    const float* ks = kp + klk;
    for (int jj = 0; jj < 8; ++jj) kreg[jj] = ks[(size_t)(kd0 + jj) * LL];
    vreg[0] = *(const float4*)(vp + (size_t)vd * LL + vc8);
    vreg[1] = *(const float4*)(vp + (size_t)vd * LL + vc8 + 4);
  }

  __syncthreads();
  bf16x8 bq[4];
  for (int kk = 0; kk < 4; ++kk)
    bq[kk] = *(const bf16x8*)&sm.a.Qs[wbase + l31][kk * 16 + 8 * hh];

  f32x16 oacc[2];
  for (int dt = 0; dt < 2; ++dt)
    for (int r = 0; r < 16; ++r) oacc[dt][r] = 0.f;
  float rsum = 0.f;

  for (int t = 0; t < LL / TK; ++t) {
    __syncthreads();
    {
      bf16x8 pk;
      for (int jj = 0; jj < 8; ++jj) pk[jj] = (bf16_t)kreg[jj];
      *(bf16x8*)&sm.a.Ks[klk][kd0] = pk;
      bf16x8 pv;
      pv[0] = (bf16_t)vreg[0].x; pv[1] = (bf16_t)vreg[0].y;
      pv[2] = (bf16_t)vreg[0].z; pv[3] = (bf16_t)vreg[0].w;
      pv[4] = (bf16_t)vreg[1].x; pv[5] = (bf16_t)vreg[1].y;
      pv[6] = (bf16_t)vreg[1].z; pv[7] = (bf16_t)vreg[1].w;
      *(bf16x8*)&sm.a.Vs[vd][vc8] = pv;
    }
    __syncthreads();

    if (t + 1 < LL / TK) {
      const int lk0n = (t + 1) * TK;
      const float* ks = kp + lk0n + klk;
      for (int jj = 0; jj < 8; ++jj) kreg[jj] = ks[(size_t)(kd0 + jj) * LL];
      vreg[0] = *(const float4*)(vp + (size_t)vd * LL + lk0n + vc8);
      vreg[1] = *(const float4*)(vp + (size_t)vd * LL + lk0n + vc8 + 4);
    }

    f32x16 st;
    for (int r = 0; r < 16; ++r) st[r] = 0.f;
    for (int kk = 0; kk < 4; ++kk) {
      bf16x8 akf = *(const bf16x8*)&sm.a.Ks[lkh + l31][kk * 16 + 8 * hh];
      st = __builtin_amdgcn_mfma_f32_32x32x16_bf16(akf, bq[kk], st, 0, 0, 0);
    }

    unsigned pb[8];
    for (int r = 0; r < 16; ++r) {
      float s = st[r];
      s = fmaxf(s, 0.01f * s);
      float p = __builtin_amdgcn_exp2f(s);
      rsum += p;
      st[r] = p;
    }
    for (int qq = 0; qq < 8; ++qq) {
      union { bf16_t b[2]; unsigned u; } pk;
      pk.b[0] = (bf16_t)st[2 * qq];
      pk.b[1] = (bf16_t)st[2 * qq + 1];
      pb[qq] = pk.u;
    }

    for (int kk2 = 0; kk2 < 2; ++kk2) {
      unsigned l0 = pb[4 * kk2 + 0], l1 = pb[4 * kk2 + 1];
      unsigned l2 = pb[4 * kk2 + 2], l3 = pb[4 * kk2 + 3];
      unsigned s0 = hh ? l0 : l2;
      unsigned s1 = hh ? l1 : l3;
      unsigned f0 = (unsigned)__shfl_xor((int)s0, 32);
      unsigned f1 = (unsigned)__shfl_xor((int)s1, 32);
      union { unsigned u[4]; bf16x8 v; } ap;
      ap.u[0] = hh ? f0 : l0;
      ap.u[1] = hh ? f1 : l1;
      ap.u[2] = hh ? l2 : f0;
      ap.u[3] = hh ? l3 : f1;
      const int lkb = lkh + kk2 * 16 + 8 * hh;
      for (int dt = 0; dt < 2; ++dt) {
        bf16x8 bvf = *(const bf16x8*)&sm.a.Vs[dt * 32 + l31][lkb];
        oacc[dt] = __builtin_amdgcn_mfma_f32_32x32x16_bf16(ap.v, bvf, oacc[dt], 0, 0, 0);
      }
    }
  }

  float rtot = rsum + __shfl_xor(rsum, 32);
  __syncthreads();
  if (half == 1) {
    rs1[wbase + l31] = rtot;
    for (int r = 0; r < 16; ++r) {
      int row = (r & 3) + 8 * (r >> 2) + 4 * hh;
      for (int dt = 0; dt < 2; ++dt)
        sm.Oe[wbase + row][dt * 32 + l31] = oacc[dt][r];
    }
  }
  __syncthreads();
  if (half == 0) {
    float tot = rtot + rs1[wbase + l31];
    rs1[wbase + l31] = 1.0f / tot;
    float inv[16];
    for (int r = 0; r < 16; ++r) {
      int row = (r & 3) + 8 * (r >> 2) + 4 * hh;
      inv[r] = rs1[wbase + row];
    }
    for (int r = 0; r < 16; ++r) {
      int row = (r & 3) + 8 * (r >> 2) + 4 * hh;
      for (int dt = 0; dt < 2; ++dt) {
        int col = dt * 32 + l31;
        sm.Oe[wbase + row][col] = (oacc[dt][r] + sm.Oe[wbase + row][col]) * inv[r];
      }
    }
  }
  __syncthreads();
  float* op = out + hoff + q0;
  for (int i = 0; i < 16; ++i) {
    int idx = tid + NTHREADS * i;
    int d   = idx >> 7;
    int lq  = idx & 127;
    op[(size_t)d * LL + lq] = sm.Oe[lq][d];
  }
}

extern "C" void kernel_launch(void* const* d_in, const int* in_sizes, int n_in,
                              void* d_out, int out_size, void* d_ws, size_t ws_size,
                              hipStream_t stream) {
  const float* q = (const float*)d_in[0];
  const float* k = (const float*)d_in[1];
  const float* v = (const float*)d_in[2];
  float* out = (float*)d_out;
  const size_t per_buf = (size_t)HEADS * DD * LL;           // elements
  const size_t need = 2 * per_buf * sizeof(bf16_t);         // 16.8 MB (K,V only)
  if (d_ws && ws_size >= need) {
    bf16_t* kt = (bf16_t*)d_ws;
    bf16_t* vt = kt + per_buf;
    prep_bf16_kv2<<<dim3(LL / 64, HEADS, 2), 256, 0, stream>>>(k, v, kt, vt);
    attn_flash_nolds<<<dim3((LL / TQ) * HEADS), NTHREADS, 0, stream>>>(q, kt, vt, out);
  } else {
    attn_flash_bf16<<<dim3(LL / TQ, HEADS), NTHREADS, 0, stream>>>(q, k, v, out);
  }
}

// Round 8
// 143.793 us; speedup vs baseline: 1.4361x; 1.4361x over previous
//
#include <hip/hip_runtime.h>
#include <math.h>

#define DD 64
#define LL 2048
#define HEADS 32
#define TQ 128
#define TK 64
#define NT (LL / TK)             // 32 k-tiles
#define NTHREADS 512
// 1/sqrt(64) * log2(e), folded into Q at staging (leaky commutes with positive scale)
#define QSCALE 0.18033688011112042f

typedef __bf16 bf16_t;
typedef __bf16 bf16x8 __attribute__((ext_vector_type(8)));
typedef float f32x16 __attribute__((ext_vector_type(16)));

// ============================================================================
// Prepass (K,V only — Q has no cross-block reuse, main kernel stages it):
//   z=0: KT[head][l][d] = k[head][d][l]   (transposed, bf16)
//   z=1: VB[head][d][l] = v[head][d][l]   (straight convert, bf16)
// ~33.5 MB read + 16.8 MB write => ~8 us memory-bound.
// ============================================================================
__global__ __launch_bounds__(256)
void prep_bf16_kv(const float* __restrict__ k, const float* __restrict__ v,
                  bf16_t* __restrict__ kt, bf16_t* __restrict__ vb) {
  __shared__ float ld[64][65];
  const int t = threadIdx.x;
  const int which = blockIdx.z;
  const int head = blockIdx.y;
  const int l0 = blockIdx.x * 64;
  const size_t hoff = (size_t)head * DD * LL;
  if (which == 1) {
    const float* src = v + hoff;
    bf16_t* dst = vb + hoff;
    const int lp = (t & 31) * 2;
    const int db = (t >> 5) * 8;
    for (int i = 0; i < 8; ++i) {
      int d = db + i;
      float2 x = *(const float2*)(src + (size_t)d * LL + l0 + lp);
      union { bf16_t b[2]; unsigned u; } pk;
      pk.b[0] = (bf16_t)x.x;
      pk.b[1] = (bf16_t)x.y;
      *(unsigned*)(dst + (size_t)d * LL + l0 + lp) = pk.u;
    }
  } else {
    const float* src = k + hoff;
    bf16_t* dst = kt + hoff;
    const int l = t & 63;
    const int db = (t >> 6) * 16;
    for (int i = 0; i < 16; ++i) {
      int d = db + i;
      ld[l][d] = src[(size_t)d * LL + l0 + l];  // coalesced along l
    }
    __syncthreads();
    const int dp = (t & 31) * 2;
    const int lb = (t >> 5) * 8;
    for (int i = 0; i < 8; ++i) {
      int lw = lb + i;
      union { bf16_t b[2]; unsigned u; } pk;
      pk.b[0] = (bf16_t)ld[lw][dp];
      pk.b[1] = (bf16_t)ld[lw][dp + 1];
      *(unsigned*)(dst + (size_t)(l0 + lw) * DD + dp) = pk.u;  // coalesced along d
    }
  }
}

// ============================================================================
// Main kernel v9: v5 structure + T15 two-tile software pipeline.
// Iteration t computes QK(t) into stc AND softmax+PV(t-1) from stp —
// disjoint registers, so the QK MFMA chain (matrix pipe) runs concurrently
// with softmax (VALU pipe) instead of serializing. Commit pair per iter is
// {K(t), V(t-1)}: V slot (t-1)&1's prior reader was PV(t-3), two barriers
// back => still exactly ONE barrier per tile, LDS unchanged (37.4 KB).
// Keeps: XCD head pinning, K/V-only prepass, fp32 Q staged in-kernel,
// Qs unioned into Ks dbuf, rsl[4] split sums, setprio on MFMA clusters.
// ============================================================================
struct __align__(16) SMemA4 {
  union {
    bf16_t Qs[TQ][72];       // [lq][d] pre-scaled bf16 (dead after bq hoist)
    bf16_t Ks[2][TK][72];    // double-buffered [lk][d]
  } qk;
  bf16_t Vs[2][DD][72];      // double-buffered [d][lk]
};
union __align__(16) SMemU4 {
  SMemA4 a;
  float Oe[TQ][65];          // epilogue combine/transpose buffer (33.3 KB)
};

// softmax(stp) -> pb, accumulate rsl
#define SOFTMAX_PACK(STP, PB)                                  \
  do {                                                         \
    _Pragma("unroll")                                          \
    for (int r = 0; r < 16; ++r) {                             \
      float s = (STP)[r];                                      \
      s = fmaxf(s, 0.01f * s);                                 \
      float p = __builtin_amdgcn_exp2f(s);                     \
      rsl[r & 3] += p;                                         \
      (STP)[r] = p;                                            \
    }                                                          \
    for (int qq = 0; qq < 8; ++qq) {                           \
      union { bf16_t b[2]; unsigned u; } pk;                   \
      pk.b[0] = (bf16_t)(STP)[2 * qq];                         \
      pk.b[1] = (bf16_t)(STP)[2 * qq + 1];                     \
      (PB)[qq] = pk.u;                                         \
    }                                                          \
  } while (0)

// PV from pb, reading V slot VS
#define PV_STEP(PB, VS)                                                         \
  do {                                                                          \
    for (int kk2 = 0; kk2 < 2; ++kk2) {                                         \
      unsigned l0 = (PB)[4 * kk2 + 0], l1 = (PB)[4 * kk2 + 1];                  \
      unsigned l2 = (PB)[4 * kk2 + 2], l3 = (PB)[4 * kk2 + 3];                  \
      unsigned s0 = hh ? l0 : l2;                                               \
      unsigned s1 = hh ? l1 : l3;                                               \
      unsigned f0 = (unsigned)__shfl_xor((int)s0, 32);                          \
      unsigned f1 = (unsigned)__shfl_xor((int)s1, 32);                          \
      union { unsigned u[4]; bf16x8 v; } ap;                                    \
      ap.u[0] = hh ? f0 : l0;                                                   \
      ap.u[1] = hh ? f1 : l1;                                                   \
      ap.u[2] = hh ? l2 : f0;                                                   \
      ap.u[3] = hh ? l3 : f1;                                                   \
      const int lkb = lkh + kk2 * 16 + 8 * hh;                                  \
      __builtin_amdgcn_s_setprio(1);                                            \
      for (int dt = 0; dt < 2; ++dt) {                                          \
        bf16x8 bv = *(const bf16x8*)&sm.a.Vs[VS][dt * 32 + l31][lkb];           \
        oacc[dt] = __builtin_amdgcn_mfma_f32_32x32x16_bf16(ap.v, bv,            \
                                                           oacc[dt], 0, 0, 0); \
      }                                                                         \
      __builtin_amdgcn_s_setprio(0);                                            \
    }                                                                           \
  } while (0)

__global__ __launch_bounds__(NTHREADS, 4)
void attn_flash_bf16_v9(const float* __restrict__ q, const bf16_t* __restrict__ kt,
                        const bf16_t* __restrict__ vb, float* __restrict__ out) {
  __shared__ SMemU4 sm;
  __shared__ float rs1[TQ];
  const int tid  = threadIdx.x;
  const int w    = tid >> 6;        // wave 0..7
  const int lane = tid & 63;
  const int l31  = lane & 31;
  const int hh   = lane >> 5;       // half of wave
  const int strip = w & 3;          // lq strip 0..3
  const int half  = w >> 2;         // lk half 0/1
  const int wbase = strip * 32;
  const int lkh   = half * 32;
  // ---- XCD-aware decode: bid%8 pins head%8 => per-XCD L2-resident K/V ----
  const int bid  = blockIdx.x;
  const int j    = bid >> 3;
  const int head = (bid & 7) + 8 * (j >> 4);
  const int q0   = (j & 15) * TQ;
  const size_t hoff = (size_t)head * DD * LL;
  const float*  qp = q  + hoff;
  const bf16_t* kp = kt + hoff;
  const bf16_t* vp = vb + hoff;

  // staging coords: K transpose rows + V natural rows, 16B per thread each
  const int srow = tid >> 3;        // 0..63 (lk for K, d for V)
  const int scol = (tid & 7) * 8;

  // ---- prefetch K(0), V(0) (in flight under Q staging) ----
  bf16x8 kreg = *(const bf16x8*)(kp + (size_t)srow * DD + scol);
  bf16x8 vreg = *(const bf16x8*)(vp + (size_t)srow * LL + scol);

  // ---- stage Q transposed from fp32: lanes along lq => coalesced 512B lines ----
  {
    int lq  = tid & 127;
    int d0q = (tid >> 7) * 16;
    const float* src = qp + q0 + lq;
    for (int g = 0; g < 2; ++g) {
      bf16x8 pk;
      for (int jj = 0; jj < 8; ++jj)
        pk[jj] = (bf16_t)(src[(size_t)(d0q + g * 8 + jj) * LL] * QSCALE);
      *(bf16x8*)&sm.a.qk.Qs[lq][d0q + g * 8] = pk;
    }
  }

  __syncthreads();   // Q staged
  bf16x8 bq[4];
  for (int kk = 0; kk < 4; ++kk)
    bq[kk] = *(const bf16x8*)&sm.a.qk.Qs[wbase + l31][kk * 16 + 8 * hh];
  __syncthreads();   // ALL waves done reading Qs; aliased Ks writes now safe

  f32x16 oacc[2];
  for (int dt = 0; dt < 2; ++dt)
    for (int r = 0; r < 16; ++r) oacc[dt][r] = 0.f;
  float rsl[4];
  for (int i = 0; i < 4; ++i) rsl[i] = 0.f;

  // ---- prologue: commit K(0), QK(0) -> stp, load K(1) ----
  f32x16 stp;
  {
    *(bf16x8*)&sm.a.qk.Ks[0][srow][scol] = kreg;
    __syncthreads();
    for (int r = 0; r < 16; ++r) stp[r] = 0.f;
    __builtin_amdgcn_s_setprio(1);
    for (int kk = 0; kk < 4; ++kk) {
      bf16x8 ak = *(const bf16x8*)&sm.a.qk.Ks[0][lkh + l31][kk * 16 + 8 * hh];
      stp = __builtin_amdgcn_mfma_f32_32x32x16_bf16(ak, bq[kk], stp, 0, 0, 0);
    }
    __builtin_amdgcn_s_setprio(0);
    kreg = *(const bf16x8*)(kp + (size_t)(TK + srow) * DD + scol);   // K(1)
    // vreg still holds V(0)
  }

  // ---- pipelined main loop: iter t = QK(t) || softmax+PV(t-1) ----
  for (int t = 1; t < NT; ++t) {
    const int cur = t & 1;
    // commit K(t) and V(t-1). V slot cur^1 last read by PV(t-3) two barriers ago.
    *(bf16x8*)&sm.a.qk.Ks[cur][srow][scol]  = kreg;
    *(bf16x8*)&sm.a.Vs[cur ^ 1][srow][scol] = vreg;
    __syncthreads();

    // QK(t) -> stc (independent of stp: MFMA pipe runs under softmax VALU)
    f32x16 stc;
    for (int r = 0; r < 16; ++r) stc[r] = 0.f;
    __builtin_amdgcn_s_setprio(1);
    for (int kk = 0; kk < 4; ++kk) {
      bf16x8 ak = *(const bf16x8*)&sm.a.qk.Ks[cur][lkh + l31][kk * 16 + 8 * hh];
      stc = __builtin_amdgcn_mfma_f32_32x32x16_bf16(ak, bq[kk], stc, 0, 0, 0);
    }
    __builtin_amdgcn_s_setprio(0);

    // issue loads K(t+1) (clamped) and V(t): land by next iter's commit
    {
      const int tn = (t + 1 < NT) ? t + 1 : t;
      kreg = *(const bf16x8*)(kp + (size_t)(tn * TK + srow) * DD + scol);
      vreg = *(const bf16x8*)(vp + (size_t)srow * LL + t * TK + scol);
    }

    // softmax + PV of tile t-1 (from stp, V slot cur^1)
    unsigned pb[8];
    SOFTMAX_PACK(stp, pb);
    PV_STEP(pb, cur ^ 1);

    stp = stc;   // SSA rename; no dynamic indexing
  }

  // ---- epilogue peel: commit V(31), softmax+PV(31) ----
  {
    *(bf16x8*)&sm.a.Vs[(NT - 1) & 1][srow][scol] = vreg;
    __syncthreads();
    unsigned pb[8];
    SOFTMAX_PACK(stp, pb);
    PV_STEP(pb, (NT - 1) & 1);
  }

  // ---- epilogue: combine lk-half pairs, normalize, transpose, store ----
  float rsum = (rsl[0] + rsl[1]) + (rsl[2] + rsl[3]);
  float rtot = rsum + __shfl_xor(rsum, 32);   // both hh row-groups of this wave
  __syncthreads();                            // all compute LDS reads done; union safe
  if (half == 1) {
    rs1[wbase + l31] = rtot;
    for (int r = 0; r < 16; ++r) {
      int row = (r & 3) + 8 * (r >> 2) + 4 * hh;
      for (int dt = 0; dt < 2; ++dt)
        sm.Oe[wbase + row][dt * 32 + l31] = oacc[dt][r];
    }
  }
  __syncthreads();
  if (half == 0) {
    float tot = rtot + rs1[wbase + l31];
    rs1[wbase + l31] = 1.0f / tot;            // same-lane read-then-write: safe in-wave
    float inv[16];
    for (int r = 0; r < 16; ++r) {
      int row = (r & 3) + 8 * (r >> 2) + 4 * hh;
      inv[r] = rs1[wbase + row];              // in-wave broadcast reads
    }
    for (int r = 0; r < 16; ++r) {
      int row = (r & 3) + 8 * (r >> 2) + 4 * hh;
      for (int dt = 0; dt < 2; ++dt) {
        int col = dt * 32 + l31;
        sm.Oe[wbase + row][col] = (oacc[dt][r] + sm.Oe[wbase + row][col]) * inv[r];
      }
    }
  }
  __syncthreads();
  float* op = out + hoff + q0;
  for (int i = 0; i < 16; ++i) {
    int idx = tid + NTHREADS * i;  // 0..8191
    int d   = idx >> 7;
    int lq  = idx & 127;
    op[(size_t)d * LL + lq] = sm.Oe[lq][d];   // coalesced: lanes -> consecutive lq
  }
}

// ============================================================================
// Fallback: the original harness-verified fp32-input kernel (no workspace).
// ============================================================================
struct __align__(16) SMemA {
  bf16_t Qs[TQ][72];
  bf16_t Ks[TK][72];
  bf16_t Vs[DD][72];
};
union __align__(16) SMemU {
  SMemA a;
  float Oe[TQ][65];
};

__global__ __launch_bounds__(NTHREADS, 4)
void attn_flash_bf16(const float* __restrict__ q, const float* __restrict__ k,
                     const float* __restrict__ v, float* __restrict__ out) {
  __shared__ SMemU sm;
  __shared__ float rs1[TQ];
  const int tid  = threadIdx.x;
  const int w    = tid >> 6;
  const int lane = tid & 63;
  const int l31  = lane & 31;
  const int hh   = lane >> 5;
  const int strip = w & 3;
  const int half  = w >> 2;
  const int wbase = strip * 32;
  const int lkh   = half * 32;
  const int head = blockIdx.y;
  const int q0   = blockIdx.x * TQ;
  const size_t hoff = (size_t)head * DD * LL;
  const float* qp = q + hoff;
  const float* kp = k + hoff;
  const float* vp = v + hoff;

  {
    int lq  = tid & 127;
    int d0q = (tid >> 7) * 16;
    const float* src = qp + q0 + lq;
    for (int g = 0; g < 2; ++g) {
      bf16x8 pk;
      for (int jj = 0; jj < 8; ++jj)
        pk[jj] = (bf16_t)(src[(size_t)(d0q + g * 8 + jj) * LL] * QSCALE);
      *(bf16x8*)&sm.a.Qs[lq][d0q + g * 8] = pk;
    }
  }

  const int klk = tid & 63;
  const int kd0 = (tid >> 6) * 8;
  const int vd  = tid >> 3;
  const int vc8 = (tid & 7) * 8;

  float  kreg[8];
  float4 vreg[2];
  {
    const float* ks = kp + klk;
    for (int jj = 0; jj < 8; ++jj) kreg[jj] = ks[(size_t)(kd0 + jj) * LL];
    vreg[0] = *(const float4*)(vp + (size_t)vd * LL + vc8);
    vreg[1] = *(const float4*)(vp + (size_t)vd * LL + vc8 + 4);
  }

  __syncthreads();
  bf16x8 bq[4];
  for (int kk = 0; kk < 4; ++kk)
    bq[kk] = *(const bf16x8*)&sm.a.Qs[wbase + l31][kk * 16 + 8 * hh];

  f32x16 oacc[2];
  for (int dt = 0; dt < 2; ++dt)
    for (int r = 0; r < 16; ++r) oacc[dt][r] = 0.f;
  float rsum = 0.f;

  for (int t = 0; t < LL / TK; ++t) {
    __syncthreads();
    {
      bf16x8 pk;
      for (int jj = 0; jj < 8; ++jj) pk[jj] = (bf16_t)kreg[jj];
      *(bf16x8*)&sm.a.Ks[klk][kd0] = pk;
      bf16x8 pv;
      pv[0] = (bf16_t)vreg[0].x; pv[1] = (bf16_t)vreg[0].y;
      pv[2] = (bf16_t)vreg[0].z; pv[3] = (bf16_t)vreg[0].w;
      pv[4] = (bf16_t)vreg[1].x; pv[5] = (bf16_t)vreg[1].y;
      pv[6] = (bf16_t)vreg[1].z; pv[7] = (bf16_t)vreg[1].w;
      *(bf16x8*)&sm.a.Vs[vd][vc8] = pv;
    }
    __syncthreads();

    if (t + 1 < LL / TK) {
      const int lk0n = (t + 1) * TK;
      const float* ks = kp + lk0n + klk;
      for (int jj = 0; jj < 8; ++jj) kreg[jj] = ks[(size_t)(kd0 + jj) * LL];
      vreg[0] = *(const float4*)(vp + (size_t)vd * LL + lk0n + vc8);
      vreg[1] = *(const float4*)(vp + (size_t)vd * LL + lk0n + vc8 + 4);
    }

    f32x16 st;
    for (int r = 0; r < 16; ++r) st[r] = 0.f;
    for (int kk = 0; kk < 4; ++kk) {
      bf16x8 akf = *(const bf16x8*)&sm.a.Ks[lkh + l31][kk * 16 + 8 * hh];
      st = __builtin_amdgcn_mfma_f32_32x32x16_bf16(akf, bq[kk], st, 0, 0, 0);
    }

    unsigned pb[8];
    for (int r = 0; r < 16; ++r) {
      float s = st[r];
      s = fmaxf(s, 0.01f * s);
      float p = __builtin_amdgcn_exp2f(s);
      rsum += p;
      st[r] = p;
    }
    for (int qq = 0; qq < 8; ++qq) {
      union { bf16_t b[2]; unsigned u; } pk;
      pk.b[0] = (bf16_t)st[2 * qq];
      pk.b[1] = (bf16_t)st[2 * qq + 1];
      pb[qq] = pk.u;
    }

    for (int kk2 = 0; kk2 < 2; ++kk2) {
      unsigned l0 = pb[4 * kk2 + 0], l1 = pb[4 * kk2 + 1];
      unsigned l2 = pb[4 * kk2 + 2], l3 = pb[4 * kk2 + 3];
      unsigned s0 = hh ? l0 : l2;
      unsigned s1 = hh ? l1 : l3;
      unsigned f0 = (unsigned)__shfl_xor((int)s0, 32);
      unsigned f1 = (unsigned)__shfl_xor((int)s1, 32);
      union { unsigned u[4]; bf16x8 v; } ap;
      ap.u[0] = hh ? f0 : l0;
      ap.u[1] = hh ? f1 : l1;
      ap.u[2] = hh ? l2 : f0;
      ap.u[3] = hh ? l3 : f1;
      const int lkb = lkh + kk2 * 16 + 8 * hh;
      for (int dt = 0; dt < 2; ++dt) {
        bf16x8 bvf = *(const bf16x8*)&sm.a.Vs[dt * 32 + l31][lkb];
        oacc[dt] = __builtin_amdgcn_mfma_f32_32x32x16_bf16(ap.v, bvf, oacc[dt], 0, 0, 0);
      }
    }
  }

  float rtot = rsum + __shfl_xor(rsum, 32);
  __syncthreads();
  if (half == 1) {
    rs1[wbase + l31] = rtot;
    for (int r = 0; r < 16; ++r) {
      int row = (r & 3) + 8 * (r >> 2) + 4 * hh;
      for (int dt = 0; dt < 2; ++dt)
        sm.Oe[wbase + row][dt * 32 + l31] = oacc[dt][r];
    }
  }
  __syncthreads();
  if (half == 0) {
    float tot = rtot + rs1[wbase + l31];
    rs1[wbase + l31] = 1.0f / tot;
    float inv[16];
    for (int r = 0; r < 16; ++r) {
      int row = (r & 3) + 8 * (r >> 2) + 4 * hh;
      inv[r] = rs1[wbase + row];
    }
    for (int r = 0; r < 16; ++r) {
      int row = (r & 3) + 8 * (r >> 2) + 4 * hh;
      for (int dt = 0; dt < 2; ++dt) {
        int col = dt * 32 + l31;
        sm.Oe[wbase + row][col] = (oacc[dt][r] + sm.Oe[wbase + row][col]) * inv[r];
      }
    }
  }
  __syncthreads();
  float* op = out + hoff + q0;
  for (int i = 0; i < 16; ++i) {
    int idx = tid + NTHREADS * i;
    int d   = idx >> 7;
    int lq  = idx & 127;
    op[(size_t)d * LL + lq] = sm.Oe[lq][d];
  }
}

extern "C" void kernel_launch(void* const* d_in, const int* in_sizes, int n_in,
                              void* d_out, int out_size, void* d_ws, size_t ws_size,
                              hipStream_t stream) {
  const float* q = (const float*)d_in[0];
  const float* k = (const float*)d_in[1];
  const float* v = (const float*)d_in[2];
  float* out = (float*)d_out;
  const size_t per_buf = (size_t)HEADS * DD * LL;           // elements
  const size_t need = 2 * per_buf * sizeof(bf16_t);         // 16.8 MB (K,V only)
  if (d_ws && ws_size >= need) {
    bf16_t* kt = (bf16_t*)d_ws;
    bf16_t* vb = kt + per_buf;
    prep_bf16_kv<<<dim3(LL / 64, HEADS, 2), 256, 0, stream>>>(k, v, kt, vb);
    attn_flash_bf16_v9<<<dim3((LL / TQ) * HEADS), NTHREADS, 0, stream>>>(q, kt, vb, out);
  } else {
    attn_flash_bf16<<<dim3(LL / TQ, HEADS), NTHREADS, 0, stream>>>(q, k, v, out);
  }
}

// Round 9
// 139.721 us; speedup vs baseline: 1.4780x; 1.0291x over previous
//
#include <hip/hip_runtime.h>
#include <math.h>

#define DD 64
#define LL 2048
#define HEADS 32
#define TQ 128
#define TQ2 256
#define TK 64
#define NT (LL / TK)             // 32 k-tiles
#define NTHREADS 512
#define NTH2 1024
// 1/sqrt(64) * log2(e), folded into Q at staging (leaky commutes with positive scale)
#define QSCALE 0.18033688011112042f

typedef __bf16 bf16_t;
typedef __bf16 bf16x8 __attribute__((ext_vector_type(8)));
typedef float f32x16 __attribute__((ext_vector_type(16)));
typedef int i32x2 __attribute__((ext_vector_type(2)));

// ============================================================================
// Prepass (K,V only — Q has no cross-block reuse, main kernel stages it):
//   z=0: KT[head][l][d] = k[head][d][l]   (transposed, bf16)
//   z=1: VB[head][d][l] = v[head][d][l]   (straight convert, bf16)
// ~33.5 MB read + 16.8 MB write => ~8-10 us memory-bound.
// ============================================================================
__global__ __launch_bounds__(256)
void prep_bf16_kv(const float* __restrict__ k, const float* __restrict__ v,
                  bf16_t* __restrict__ kt, bf16_t* __restrict__ vb) {
  __shared__ float ld[64][65];
  const int t = threadIdx.x;
  const int which = blockIdx.z;
  const int head = blockIdx.y;
  const int l0 = blockIdx.x * 64;
  const size_t hoff = (size_t)head * DD * LL;
  if (which == 1) {
    const float* src = v + hoff;
    bf16_t* dst = vb + hoff;
    const int lp = (t & 31) * 2;
    const int db = (t >> 5) * 8;
    for (int i = 0; i < 8; ++i) {
      int d = db + i;
      float2 x = *(const float2*)(src + (size_t)d * LL + l0 + lp);
      union { bf16_t b[2]; unsigned u; } pk;
      pk.b[0] = (bf16_t)x.x;
      pk.b[1] = (bf16_t)x.y;
      *(unsigned*)(dst + (size_t)d * LL + l0 + lp) = pk.u;
    }
  } else {
    const float* src = k + hoff;
    bf16_t* dst = kt + hoff;
    const int l = t & 63;
    const int db = (t >> 6) * 16;
    for (int i = 0; i < 16; ++i) {
      int d = db + i;
      ld[l][d] = src[(size_t)d * LL + l0 + l];  // coalesced along l
    }
    __syncthreads();
    const int dp = (t & 31) * 2;
    const int lb = (t >> 5) * 8;
    for (int i = 0; i < 8; ++i) {
      int lw = lb + i;
      union { bf16_t b[2]; unsigned u; } pk;
      pk.b[0] = (bf16_t)ld[lw][dp];
      pk.b[1] = (bf16_t)ld[lw][dp + 1];
      *(unsigned*)(dst + (size_t)(l0 + lw) * DD + dp) = pk.u;  // coalesced along d
    }
  }
}

// ============================================================================
// Main kernel v10: TQ=256, 1024 threads (16 waves = 8 lq-strips x 2 lk-halves).
// Rationale: three structural nulls at 65 us (split-K, occupancy, T15) say the
// cost is per-STAGED-TILE overhead, not parallelism/ordering. Doubling the
// q-rows amortizing each K/V tile halves staging instructions, barriers, and
// Q/epilogue work per unit of output:
//   - threads 0-511 stage K, 512-1023 stage V: ONE load + ONE ds_write per
//     thread per tile (v5: two each).
//   - LDS strides byte-identical to v5 ([..][72] rows — the empirically
//     conflict-free layout; r5's regression came from a 136-elem stride).
//   - PV cross-half exchange via permlane32_swap (4 inst replace 16 cndmask +
//     4 ds_bpermute); shfl fallback if builtin missing.
//   - grid = 256 blocks (1/CU), still 16 waves/CU. XCD pinning kept.
// ============================================================================
struct __align__(16) SMemA10 {
  union {
    bf16_t Qs[TQ2][72];      // [lq][d] pre-scaled bf16 (dead after bq hoist) 36.9KB
    bf16_t Ks[2][64][72];    // double-buffered [lk][d] 18.4KB
  } qk;
  bf16_t Vs[2][64][72];      // double-buffered [d][lk] 18.4KB
};
union __align__(16) SMemU10 {
  SMemA10 a;
  float Oe[TQ2][65];         // epilogue combine/transpose buffer 66.6KB
};

__global__ __launch_bounds__(NTH2, 4)
void attn_flash_bf16_v10(const float* __restrict__ q, const bf16_t* __restrict__ kt,
                         const bf16_t* __restrict__ vb, float* __restrict__ out) {
  __shared__ SMemU10 sm;
  __shared__ float rs1[TQ2];
  const int tid  = threadIdx.x;
  const int w    = tid >> 6;        // wave 0..15
  const int lane = tid & 63;
  const int l31  = lane & 31;
  const int hh   = lane >> 5;       // half of wave
  const int strip = w & 7;          // lq strip 0..7
  const int half  = w >> 3;         // lk half 0/1
  const int wbase = strip * 32;
  const int lkh   = half * 32;
  // ---- XCD-aware decode: bid%8 pins head%8 => per-XCD L2-resident K/V ----
  const int bid  = blockIdx.x;      // 0..255
  const int j    = bid >> 3;        // 0..31
  const int head = (bid & 7) + 8 * (j >> 3);
  const int q0   = (j & 7) * TQ2;
  const size_t hoff = (size_t)head * DD * LL;
  const float*  qp = q  + hoff;
  const bf16_t* kp = kt + hoff;
  const bf16_t* vp = vb + hoff;

  // ---- staging role: waves 0-7 stage K, waves 8-15 stage V; 16B per thread ----
  const int sk   = tid >> 9;        // 0 = K, 1 = V (wave-uniform)
  const int stid = tid & 511;
  const int srow = stid >> 3;       // 0..63 (lk for K, d for V)
  const int scol = (stid & 7) * 8;
  const bf16_t* sbase = sk ? (vp + (size_t)srow * LL + scol)
                           : (kp + (size_t)srow * DD + scol);
  const size_t sstep = sk ? (size_t)TK : (size_t)TK * DD;   // per-tile advance
  bf16_t* sdst0 = sk ? &sm.a.Vs[0][srow][scol] : &sm.a.qk.Ks[0][srow][scol];
  bf16_t* sdst1 = sk ? &sm.a.Vs[1][srow][scol] : &sm.a.qk.Ks[1][srow][scol];

  // ---- prefetch tile 0 (in flight under Q staging) ----
  bf16x8 kvreg = *(const bf16x8*)sbase;

  // ---- stage Q transposed from fp32: lanes along lq => coalesced 1KB lines ----
  {
    int lq  = tid & 255;
    int d0q = (tid >> 8) * 16;      // 0,16,32,48
    const float* src = qp + q0 + lq;
    for (int g = 0; g < 2; ++g) {
      bf16x8 pk;
      for (int jj = 0; jj < 8; ++jj)
        pk[jj] = (bf16_t)(src[(size_t)(d0q + g * 8 + jj) * LL] * QSCALE);
      *(bf16x8*)&sm.a.qk.Qs[lq][d0q + g * 8] = pk;
    }
  }

  __syncthreads();   // Q staged
  bf16x8 bq[4];
  for (int kk = 0; kk < 4; ++kk)
    bq[kk] = *(const bf16x8*)&sm.a.qk.Qs[wbase + l31][kk * 16 + 8 * hh];
  __syncthreads();   // ALL waves done reading Qs; aliased Ks writes now safe

  f32x16 oacc[2];
  for (int dt = 0; dt < 2; ++dt)
    for (int r = 0; r < 16; ++r) oacc[dt][r] = 0.f;
  float rsl[4];
  for (int i = 0; i < 4; ++i) rsl[i] = 0.f;

  for (int t = 0; t < NT; ++t) {
    const int cur = t & 1;
    // ---- commit prefetched tile (race-free single barrier: prior readers of
    //      this slot were at iter t-2, drained before iter t-1's barrier) ----
    *(bf16x8*)(cur ? sdst1 : sdst0) = kvreg;
    __syncthreads();

    // ---- issue prefetch for tile t+1 (in flight during compute) ----
    if (t + 1 < NT)
      kvreg = *(const bf16x8*)(sbase + (size_t)(t + 1) * sstep);

    // ---- S^T = K^T Q over this wave's lk half ----
    f32x16 st;
    for (int r = 0; r < 16; ++r) st[r] = 0.f;
    __builtin_amdgcn_s_setprio(1);
    for (int kk = 0; kk < 4; ++kk) {
      bf16x8 ak = *(const bf16x8*)&sm.a.qk.Ks[cur][lkh + l31][kk * 16 + 8 * hh];
      st = __builtin_amdgcn_mfma_f32_32x32x16_bf16(ak, bq[kk], st, 0, 0, 0);
    }
    __builtin_amdgcn_s_setprio(0);

    // ---- leaky + exp2 in registers (4-way split sum) ----
    unsigned pb[8];
#pragma unroll
    for (int r = 0; r < 16; ++r) {
      float s = st[r];
      s = fmaxf(s, 0.01f * s);
      float p = __builtin_amdgcn_exp2f(s);
      rsl[r & 3] += p;
      st[r] = p;
    }
    for (int qq = 0; qq < 8; ++qq) {
      union { bf16_t b[2]; unsigned u; } pk;
      pk.b[0] = (bf16_t)st[2 * qq];
      pk.b[1] = (bf16_t)st[2 * qq + 1];
      pb[qq] = pk.u;
    }

    // ---- PV over this wave's lk half: cross-half exchange ----
    for (int kk2 = 0; kk2 < 2; ++kk2) {
      unsigned x0 = pb[4 * kk2 + 0], x1 = pb[4 * kk2 + 1];
      unsigned y0 = pb[4 * kk2 + 2], y1 = pb[4 * kk2 + 3];
      union { unsigned u[4]; bf16x8 v; } ap;
#if __has_builtin(__builtin_amdgcn_permlane32_swap)
      // swap(X,Y): r[0]=[X.lo|Y.lo], r[1]=[X.hi|Y.hi] — exactly the v5 mapping
      i32x2 r0 = __builtin_amdgcn_permlane32_swap((int)x0, (int)y0, false, false);
      i32x2 r1 = __builtin_amdgcn_permlane32_swap((int)x1, (int)y1, false, false);
      ap.u[0] = (unsigned)r0[0];
      ap.u[1] = (unsigned)r1[0];
      ap.u[2] = (unsigned)r0[1];
      ap.u[3] = (unsigned)r1[1];
#else
      unsigned s0 = hh ? x0 : y0;
      unsigned s1 = hh ? x1 : y1;
      unsigned f0 = (unsigned)__shfl_xor((int)s0, 32);
      unsigned f1 = (unsigned)__shfl_xor((int)s1, 32);
      ap.u[0] = hh ? f0 : x0;
      ap.u[1] = hh ? f1 : x1;
      ap.u[2] = hh ? y0 : f0;
      ap.u[3] = hh ? y1 : f1;
#endif
      const int lkb = lkh + kk2 * 16 + 8 * hh;
      __builtin_amdgcn_s_setprio(1);
      for (int dt = 0; dt < 2; ++dt) {
        bf16x8 bv = *(const bf16x8*)&sm.a.Vs[cur][dt * 32 + l31][lkb];
        oacc[dt] = __builtin_amdgcn_mfma_f32_32x32x16_bf16(ap.v, bv, oacc[dt], 0, 0, 0);
      }
      __builtin_amdgcn_s_setprio(0);
    }
  }

  // ---- epilogue: combine lk-half pairs, normalize, transpose, store ----
  float rsum = (rsl[0] + rsl[1]) + (rsl[2] + rsl[3]);
  float rtot = rsum + __shfl_xor(rsum, 32);   // both hh row-groups of this wave
  __syncthreads();                            // all compute LDS reads done; union safe
  if (half == 1) {
    rs1[wbase + l31] = rtot;
    for (int r = 0; r < 16; ++r) {
      int row = (r & 3) + 8 * (r >> 2) + 4 * hh;
      for (int dt = 0; dt < 2; ++dt)
        sm.Oe[wbase + row][dt * 32 + l31] = oacc[dt][r];
    }
  }
  __syncthreads();
  if (half == 0) {
    float tot = rtot + rs1[wbase + l31];
    rs1[wbase + l31] = 1.0f / tot;            // same-lane read-then-write: safe in-wave
    float inv[16];
    for (int r = 0; r < 16; ++r) {
      int row = (r & 3) + 8 * (r >> 2) + 4 * hh;
      inv[r] = rs1[wbase + row];              // in-wave broadcast reads
    }
    for (int r = 0; r < 16; ++r) {
      int row = (r & 3) + 8 * (r >> 2) + 4 * hh;
      for (int dt = 0; dt < 2; ++dt) {
        int col = dt * 32 + l31;
        sm.Oe[wbase + row][col] = (oacc[dt][r] + sm.Oe[wbase + row][col]) * inv[r];
      }
    }
  }
  __syncthreads();
  float* op = out + hoff + q0;
  for (int i = 0; i < 16; ++i) {
    int idx = tid + NTH2 * i;  // 0..16383
    int d   = idx >> 8;
    int lq  = idx & 255;
    op[(size_t)d * LL + lq] = sm.Oe[lq][d];   // coalesced: lanes -> consecutive lq
  }
}

// ============================================================================
// Fallback: the original harness-verified fp32-input kernel (no workspace).
// ============================================================================
struct __align__(16) SMemA {
  bf16_t Qs[TQ][72];
  bf16_t Ks[TK][72];
  bf16_t Vs[DD][72];
};
union __align__(16) SMemU {
  SMemA a;
  float Oe[TQ][65];
};

__global__ __launch_bounds__(NTHREADS, 4)
void attn_flash_bf16(const float* __restrict__ q, const float* __restrict__ k,
                     const float* __restrict__ v, float* __restrict__ out) {
  __shared__ SMemU sm;
  __shared__ float rs1[TQ];
  const int tid  = threadIdx.x;
  const int w    = tid >> 6;
  const int lane = tid & 63;
  const int l31  = lane & 31;
  const int hh   = lane >> 5;
  const int strip = w & 3;
  const int half  = w >> 2;
  const int wbase = strip * 32;
  const int lkh   = half * 32;
  const int head = blockIdx.y;
  const int q0   = blockIdx.x * TQ;
  const size_t hoff = (size_t)head * DD * LL;
  const float* qp = q + hoff;
  const float* kp = k + hoff;
  const float* vp = v + hoff;

  {
    int lq  = tid & 127;
    int d0q = (tid >> 7) * 16;
    const float* src = qp + q0 + lq;
    for (int g = 0; g < 2; ++g) {
      bf16x8 pk;
      for (int jj = 0; jj < 8; ++jj)
        pk[jj] = (bf16_t)(src[(size_t)(d0q + g * 8 + jj) * LL] * QSCALE);
      *(bf16x8*)&sm.a.Qs[lq][d0q + g * 8] = pk;
    }
  }

  const int klk = tid & 63;
  const int kd0 = (tid >> 6) * 8;
  const int vd  = tid >> 3;
  const int vc8 = (tid & 7) * 8;

  float  kreg[8];
  float4 vreg[2];
  {
    const float* ks = kp + klk;
    for (int jj = 0; jj < 8; ++jj) kreg[jj] = ks[(size_t)(kd0 + jj) * LL];
    vreg[0] = *(const float4*)(vp + (size_t)vd * LL + vc8);
    vreg[1] = *(const float4*)(vp + (size_t)vd * LL + vc8 + 4);
  }

  __syncthreads();
  bf16x8 bq[4];
  for (int kk = 0; kk < 4; ++kk)
    bq[kk] = *(const bf16x8*)&sm.a.Qs[wbase + l31][kk * 16 + 8 * hh];

  f32x16 oacc[2];
  for (int dt = 0; dt < 2; ++dt)
    for (int r = 0; r < 16; ++r) oacc[dt][r] = 0.f;
  float rsum = 0.f;

  for (int t = 0; t < LL / TK; ++t) {
    __syncthreads();
    {
      bf16x8 pk;
      for (int jj = 0; jj < 8; ++jj) pk[jj] = (bf16_t)kreg[jj];
      *(bf16x8*)&sm.a.Ks[klk][kd0] = pk;
      bf16x8 pv;
      pv[0] = (bf16_t)vreg[0].x; pv[1] = (bf16_t)vreg[0].y;
      pv[2] = (bf16_t)vreg[0].z; pv[3] = (bf16_t)vreg[0].w;
      pv[4] = (bf16_t)vreg[1].x; pv[5] = (bf16_t)vreg[1].y;
      pv[6] = (bf16_t)vreg[1].z; pv[7] = (bf16_t)vreg[1].w;
      *(bf16x8*)&sm.a.Vs[vd][vc8] = pv;
    }
    __syncthreads();

    if (t + 1 < LL / TK) {
      const int lk0n = (t + 1) * TK;
      const float* ks = kp + lk0n + klk;
      for (int jj = 0; jj < 8; ++jj) kreg[jj] = ks[(size_t)(kd0 + jj) * LL];
      vreg[0] = *(const float4*)(vp + (size_t)vd * LL + lk0n + vc8);
      vreg[1] = *(const float4*)(vp + (size_t)vd * LL + lk0n + vc8 + 4);
    }

    f32x16 st;
    for (int r = 0; r < 16; ++r) st[r] = 0.f;
    for (int kk = 0; kk < 4; ++kk) {
      bf16x8 akf = *(const bf16x8*)&sm.a.Ks[lkh + l31][kk * 16 + 8 * hh];
      st = __builtin_amdgcn_mfma_f32_32x32x16_bf16(akf, bq[kk], st, 0, 0, 0);
    }

    unsigned pb[8];
    for (int r = 0; r < 16; ++r) {
      float s = st[r];
      s = fmaxf(s, 0.01f * s);
      float p = __builtin_amdgcn_exp2f(s);
      rsum += p;
      st[r] = p;
    }
    for (int qq = 0; qq < 8; ++qq) {
      union { bf16_t b[2]; unsigned u; } pk;
      pk.b[0] = (bf16_t)st[2 * qq];
      pk.b[1] = (bf16_t)st[2 * qq + 1];
      pb[qq] = pk.u;
    }

    for (int kk2 = 0; kk2 < 2; ++kk2) {
      unsigned l0 = pb[4 * kk2 + 0], l1 = pb[4 * kk2 + 1];
      unsigned l2 = pb[4 * kk2 + 2], l3 = pb[4 * kk2 + 3];
      unsigned s0 = hh ? l0 : l2;
      unsigned s1 = hh ? l1 : l3;
      unsigned f0 = (unsigned)__shfl_xor((int)s0, 32);
      unsigned f1 = (unsigned)__shfl_xor((int)s1, 32);
      union { unsigned u[4]; bf16x8 v; } ap;
      ap.u[0] = hh ? f0 : l0;
      ap.u[1] = hh ? f1 : l1;
      ap.u[2] = hh ? l2 : f0;
      ap.u[3] = hh ? l3 : f1;
      const int lkb = lkh + kk2 * 16 + 8 * hh;
      for (int dt = 0; dt < 2; ++dt) {
        bf16x8 bvf = *(const bf16x8*)&sm.a.Vs[dt * 32 + l31][lkb];
        oacc[dt] = __builtin_amdgcn_mfma_f32_32x32x16_bf16(ap.v, bvf, oacc[dt], 0, 0, 0);
      }
    }
  }

  float rtot = rsum + __shfl_xor(rsum, 32);
  __syncthreads();
  if (half == 1) {
    rs1[wbase + l31] = rtot;
    for (int r = 0; r < 16; ++r) {
      int row = (r & 3) + 8 * (r >> 2) + 4 * hh;
      for (int dt = 0; dt < 2; ++dt)
        sm.Oe[wbase + row][dt * 32 + l31] = oacc[dt][r];
    }
  }
  __syncthreads();
  if (half == 0) {
    float tot = rtot + rs1[wbase + l31];
    rs1[wbase + l31] = 1.0f / tot;
    float inv[16];
    for (int r = 0; r < 16; ++r) {
      int row = (r & 3) + 8 * (r >> 2) + 4 * hh;
      inv[r] = rs1[wbase + row];
    }
    for (int r = 0; r < 16; ++r) {
      int row = (r & 3) + 8 * (r >> 2) + 4 * hh;
      for (int dt = 0; dt < 2; ++dt) {
        int col = dt * 32 + l31;
        sm.Oe[wbase + row][col] = (oacc[dt][r] + sm.Oe[wbase + row][col]) * inv[r];
      }
    }
  }
  __syncthreads();
  float* op = out + hoff + q0;
  for (int i = 0; i < 16; ++i) {
    int idx = tid + NTHREADS * i;
    int d   = idx >> 7;
    int lq  = idx & 127;
    op[(size_t)d * LL + lq] = sm.Oe[lq][d];
  }
}

extern "C" void kernel_launch(void* const* d_in, const int* in_sizes, int n_in,
                              void* d_out, int out_size, void* d_ws, size_t ws_size,
                              hipStream_t stream) {
  const float* q = (const float*)d_in[0];
  const float* k = (const float*)d_in[1];
  const float* v = (const float*)d_in[2];
  float* out = (float*)d_out;
  const size_t per_buf = (size_t)HEADS * DD * LL;           // elements
  const size_t need = 2 * per_buf * sizeof(bf16_t);         // 16.8 MB (K,V only)
  if (d_ws && ws_size >= need) {
    bf16_t* kt = (bf16_t*)d_ws;
    bf16_t* vb = kt + per_buf;
    prep_bf16_kv<<<dim3(LL / 64, HEADS, 2), 256, 0, stream>>>(k, v, kt, vb);
    attn_flash_bf16_v10<<<dim3((LL / TQ2) * HEADS), NTH2, 0, stream>>>(q, kt, vb, out);
  } else {
    attn_flash_bf16<<<dim3(LL / TQ, HEADS), NTHREADS, 0, stream>>>(q, k, v, out);
  }
}